// Round 4
// baseline (229.394 us; speedup 1.0000x reference)
//
#include <hip/hip_runtime.h>

// filtfilt (4th-order IIR, 5-tap FIR) over 512 sequences of 48000.
// V4: barrier-minimal design. Wave-private LDS staging (8-chunk rounds, no
// block barriers), shuffle-based chunk-scan with one __syncthreads per
// direction, redundant per-wave P computation (benign-race LDS writes),
// heads exchange folded into barrier 1. Total block barriers: 2.

#define T48 48000
#define TP0 48030
#define SLICE4 108
// LDS float4 layout
#define HZ_OFF 40
#define WA_OFF 56
#define WB_OFF 72
#define SL_OFF 88
#define LDS_F4 (88 + 16 * SLICE4)

__global__ __launch_bounds__(1024, 4) void filtfilt_k(
    const float* __restrict__ x, const float* __restrict__ bco,
    const float* __restrict__ aco, float* __restrict__ out)
{
  __shared__ __align__(16) float4 LS[LDS_F4];
  float* LSf = reinterpret_cast<float*>(LS);

  const int c  = threadIdx.x;
  const int w  = c >> 6;
  const int ln = c & 63;
  const float* __restrict__ xs  = x + (size_t)blockIdx.x * T48;
  const float4* __restrict__ xs4 = reinterpret_cast<const float4*>(xs);
  float* __restrict__ os = out + (size_t)blockIdx.x * T48;
  float4* __restrict__ os4 = reinterpret_cast<float4*>(os);

  const float inva0 = 1.f / aco[0];
  const float b0 = bco[0]*inva0, b1 = bco[1]*inva0, b2 = bco[2]*inva0,
              b3 = bco[3]*inva0, b4 = bco[4]*inva0;
  const float na1 = -aco[1]*inva0, na2 = -aco[2]*inva0,
              na3 = -aco[3]*inva0, na4 = -aco[4]*inva0;

  // ---- P[k] = M48^(2^k): every wave computes redundantly (identical values,
  // benign race). Entry (i,j) lives at lane 4i+j (lanes 0-15 authoritative).
  {
    const int j = ln & 3, i = (ln >> 2) & 3;
    float r1 = (j==0)?1.f:0.f, r2 = (j==1)?1.f:0.f,
          r3 = (j==2)?1.f:0.f, r4 = (j==3)?1.f:0.f;
#pragma unroll
    for (int n = 0; n < 48; n++) {
      float h = fmaf(na1, r1, fmaf(na2, r2, fmaf(na3, r3, na4 * r4)));
      r4 = r3; r3 = r2; r2 = r1; r1 = h;
    }
    float Pv = (i==0)?r1 : (i==1)?r2 : (i==2)?r3 : r4;
    if (ln < 16) LSf[ln] = Pv;
#pragma unroll
    for (int k = 0; k < 9; k++) {
      float rA0 = __shfl(Pv, i*4+0), rA1 = __shfl(Pv, i*4+1),
            rA2 = __shfl(Pv, i*4+2), rA3 = __shfl(Pv, i*4+3);
      float cB0 = __shfl(Pv, 0*4+j), cB1 = __shfl(Pv, 1*4+j),
            cB2 = __shfl(Pv, 2*4+j), cB3 = __shfl(Pv, 3*4+j);
      Pv = rA0*cB0 + rA1*cB1 + rA2*cB2 + rA3*cB3;
      if (ln < 16) LSf[16*(k+1) + ln] = Pv;
    }
  }

  // ---- load staging: wave-private slice, 8 rounds of 8 chunks, 0 barriers
  float A[48];
  float w1v = 0.f, w2v = 0.f, w3v = 0.f, w4v = 0.f;
  const int sb4 = SL_OFF + w * SLICE4;
  for (int r = 0; r < 8; r++) {
    asm volatile("s_waitcnt lgkmcnt(0)" ::: "memory");
    __builtin_amdgcn_wave_barrier();
    const int c0 = 64*w + 8*r;
    const int G0 = 12*c0 - 5;
    if (G0 >= 0 && G0 <= 11902) {          // fully interior
      LS[sb4 + ln + ln/12] = xs4[G0 + ln];
      if (ln < 34) { int g = 64 + ln; LS[sb4 + g + g/12] = xs4[G0 + g]; }
    } else {                                // reflection / tail (wave-uniform)
#pragma unroll
      for (int t = 0; t < 2; t++) {
        int g = 64*t + ln;
        if (g < 98) {
          float vv[4];
#pragma unroll
          for (int e = 0; e < 4; e++) {
            int q = 4*(G0 + g) + e;
            float v = 0.f;
            if (q >= 0 && q < T48)      v = xs[q];
            else if (q < 0)             { if (q >= -15) v = 2.f*xs[0] - xs[-1 - q]; }
            else                        { if (q < T48 + 15) v = 2.f*xs[T48-1] - xs[2*T48 - 3 - q]; }
            vv[e] = v;
          }
          LS[sb4 + g + g/12] = make_float4(vv[0], vv[1], vv[2], vv[3]);
        }
      }
    }
    asm volatile("s_waitcnt lgkmcnt(0)" ::: "memory");
    __builtin_amdgcn_wave_barrier();
    if ((ln >> 3) == r) {                   // 8 owner lanes extract their chunk
      const int eb = sb4 + 13*(ln & 7);
      float4 f;
      f = LS[eb+0];  w4v = f.y; w3v = f.z; w2v = f.w;
      f = LS[eb+1];  w1v = f.x; A[0] = f.y; A[1] = f.z; A[2] = f.w;
#pragma unroll
      for (int k = 2; k <= 12; k++) {
        f = LS[eb + k + (k >= 12 ? 1 : 0)];
        A[4*k-5] = f.x; A[4*k-4] = f.y; A[4*k-3] = f.z; A[4*k-2] = f.w;
      }
      f = LS[eb+14]; A[47] = f.x;
    }
  }

  // ---- forward phase 1 (all lanes, in place, zero-state)
  float r1 = 0.f, r2 = 0.f, r3 = 0.f, r4 = 0.f;
#pragma unroll
  for (int n = 0; n < 48; n++) {
    float xv = A[n];
    float f = fmaf(b0,xv, fmaf(b1,w1v, fmaf(b2,w2v, fmaf(b3,w3v, b4*w4v))));
    w4v = w3v; w3v = w2v; w2v = w1v; w1v = xv;
    float u = fmaf(na4, r4, f);
    u = fmaf(na3, r3, u); u = fmaf(na2, r2, u); u = fmaf(na1, r1, u);
    A[n] = u; r4 = r3; r3 = r2; r2 = r1; r1 = u;
  }
  const float e0 = A[0], e1 = A[1], e2 = A[2], e3 = A[3];  // zero-state heads
  float o1 = r1, o2 = r2, o3 = r3, o4 = r4;                 // for re-scan

  // ---- forward wave-local scan (6 shuffle steps)
#pragma unroll
  for (int k = 0; k < 6; k++) {
    const float4 Pa = LS[4*k+0], Pb = LS[4*k+1], Pc = LS[4*k+2], Pd = LS[4*k+3];
    const int off = 1 << k;
    float q1 = __shfl(r1, ln-off), q2 = __shfl(r2, ln-off),
          q3 = __shfl(r3, ln-off), q4 = __shfl(r4, ln-off);
    if (ln < off) { q1 = 0.f; q2 = 0.f; q3 = 0.f; q4 = 0.f; }
    r1 += Pa.x*q1 + Pa.y*q2 + Pa.z*q3 + Pa.w*q4;
    r2 += Pb.x*q1 + Pb.y*q2 + Pb.z*q3 + Pb.w*q4;
    r3 += Pc.x*q1 + Pc.y*q2 + Pc.z*q3 + Pc.w*q4;
    r4 += Pd.x*q1 + Pd.y*q2 + Pd.z*q3 + Pd.w*q4;
  }
  if (ln == 63) LS[WA_OFF + w] = make_float4(r1, r2, r3, r4);
  if (ln == 0)  LS[HZ_OFF + w] = make_float4(e0, e1, e2, e3);
  __syncthreads();                                        // BARRIER 1

  // ---- sub-scan of 16 wave aggregates (redundant per wave, lanes 0-15)
  float W1 = 0.f, W2 = 0.f, W3 = 0.f, W4 = 0.f;
  {
    float4 Ag = LS[WA_OFF + (ln & 15)];
    float t1 = Ag.x, t2 = Ag.y, t3 = Ag.z, t4 = Ag.w;
#pragma unroll
    for (int k = 0; k < 4; k++) {
      const float4 Pa = LS[4*(6+k)+0], Pb = LS[4*(6+k)+1],
                   Pc = LS[4*(6+k)+2], Pd = LS[4*(6+k)+3];
      const int off = 1 << k;
      float q1 = __shfl(t1, ln-off), q2 = __shfl(t2, ln-off),
            q3 = __shfl(t3, ln-off), q4 = __shfl(t4, ln-off);
      if (ln < off) { q1 = 0.f; q2 = 0.f; q3 = 0.f; q4 = 0.f; }
      t1 += Pa.x*q1 + Pa.y*q2 + Pa.z*q3 + Pa.w*q4;
      t2 += Pb.x*q1 + Pb.y*q2 + Pb.z*q3 + Pb.w*q4;
      t3 += Pc.x*q1 + Pc.y*q2 + Pc.z*q3 + Pc.w*q4;
      t4 += Pd.x*q1 + Pd.y*q2 + Pd.z*q3 + Pd.w*q4;
    }
    if (w > 0) { W1 = __shfl(t1, w-1); W2 = __shfl(t2, w-1);
                 W3 = __shfl(t3, w-1); W4 = __shfl(t4, w-1); }
  }
  // inject prefix into lane 0 and re-scan
  {
    const float4 Pa = LS[0], Pb = LS[1], Pc = LS[2], Pd = LS[3];
    float i1 = Pa.x*W1 + Pa.y*W2 + Pa.z*W3 + Pa.w*W4;
    float i2 = Pb.x*W1 + Pb.y*W2 + Pb.z*W3 + Pb.w*W4;
    float i3 = Pc.x*W1 + Pc.y*W2 + Pc.z*W3 + Pc.w*W4;
    float i4 = Pd.x*W1 + Pd.y*W2 + Pd.z*W3 + Pd.w*W4;
    r1 = o1 + (ln==0 ? i1 : 0.f); r2 = o2 + (ln==0 ? i2 : 0.f);
    r3 = o3 + (ln==0 ? i3 : 0.f); r4 = o4 + (ln==0 ? i4 : 0.f);
  }
#pragma unroll
  for (int k = 0; k < 6; k++) {
    const float4 Pa = LS[4*k+0], Pb = LS[4*k+1], Pc = LS[4*k+2], Pd = LS[4*k+3];
    const int off = 1 << k;
    float q1 = __shfl(r1, ln-off), q2 = __shfl(r2, ln-off),
          q3 = __shfl(r3, ln-off), q4 = __shfl(r4, ln-off);
    if (ln < off) { q1 = 0.f; q2 = 0.f; q3 = 0.f; q4 = 0.f; }
    r1 += Pa.x*q1 + Pa.y*q2 + Pa.z*q3 + Pa.w*q4;
    r2 += Pb.x*q1 + Pb.y*q2 + Pb.z*q3 + Pb.w*q4;
    r3 += Pc.x*q1 + Pc.y*q2 + Pc.z*q3 + Pc.w*q4;
    r4 += Pd.x*q1 + Pd.y*q2 + Pd.z*q3 + Pd.w*q4;
  }
  float s1 = __shfl(r1, ln-1), s2 = __shfl(r2, ln-1),
        s3 = __shfl(r3, ln-1), s4 = __shfl(r4, ln-1);
  if (ln == 0) { s1 = W1; s2 = W2; s3 = W3; s4 = W4; }

  // ---- forward phase 2: homogeneous correction
  {
    float h1 = s1, h2 = s2, h3 = s3, h4 = s4;
#pragma unroll
    for (int n = 0; n < 48; n++) {
      float h = fmaf(na1, h1, fmaf(na2, h2, fmaf(na3, h3, na4 * h4)));
      A[n] += h;
      h4 = h3; h3 = h2; h2 = h1; h1 = h;
    }
  }
  if (c >= 1000) {
#pragma unroll
    for (int n = 0; n < 48; n++) if (48*c + n >= TP0) A[n] = 0.f;
  }

  // ---- heads: next chunk's final y[0..3] = its zero-state + hom(own S)
  float y0n = __shfl(e0, ln+1), y1n = __shfl(e1, ln+1),
        y2n = __shfl(e2, ln+1), y3n = __shfl(e3, ln+1);
  if (ln == 63) {
    float4 hz = (w < 15) ? LS[HZ_OFF + w + 1] : make_float4(0.f,0.f,0.f,0.f);
    y0n = hz.x; y1n = hz.y; y2n = hz.z; y3n = hz.w;
  }
  float h0, h1v, h2v, h3v;
  {
    float g1 = r1, g2 = r2, g3 = r3, g4 = r4, hh;
    hh = fmaf(na1,g1, fmaf(na2,g2, fmaf(na3,g3, na4*g4))); h0  = y0n + hh; g4=g3; g3=g2; g2=g1; g1=hh;
    hh = fmaf(na1,g1, fmaf(na2,g2, fmaf(na3,g3, na4*g4))); h1v = y1n + hh; g4=g3; g3=g2; g2=g1; g1=hh;
    hh = fmaf(na1,g1, fmaf(na2,g2, fmaf(na3,g3, na4*g4))); h2v = y2n + hh; g4=g3; g3=g2; g2=g1; g1=hh;
    hh = fmaf(na1,g1, fmaf(na2,g2, fmaf(na3,g3, na4*g4))); h3v = y3n + hh;
  }
  if (c >= 1000) { h0 = 0.f; h1v = 0.f; h2v = 0.f; h3v = 0.f; }

  // ---- backward phase 1 (own chunk reversed, in place)
#define YV(i) ((i) < 48 ? A[(i)] : ((i)==48 ? h0 : (i)==49 ? h1v : (i)==50 ? h2v : h3v))
  r1 = 0.f; r2 = 0.f; r3 = 0.f; r4 = 0.f;
#pragma unroll
  for (int m = 0; m < 48; m++) {
    float g = fmaf(b0, YV(47-m), fmaf(b1, YV(48-m),
              fmaf(b2, YV(49-m), fmaf(b3, YV(50-m), b4 * YV(51-m)))));
    float u = fmaf(na4, r4, g);
    u = fmaf(na3, r3, u); u = fmaf(na2, r2, u); u = fmaf(na1, r1, u);
    r4 = r3; r3 = r2; r2 = r1; r1 = u;
    if      (m == 0) h3v = u;
    else if (m == 1) h2v = u;
    else if (m == 2) h1v = u;
    else if (m == 3) h0  = u;
    else             A[51 - m] = u;
  }
#undef YV
  o1 = r1; o2 = r2; o3 = r3; o4 = r4;

  // ---- backward wave-local scan (reversed lane order)
#pragma unroll
  for (int k = 0; k < 6; k++) {
    const float4 Pa = LS[4*k+0], Pb = LS[4*k+1], Pc = LS[4*k+2], Pd = LS[4*k+3];
    const int off = 1 << k;
    float q1 = __shfl(r1, ln+off), q2 = __shfl(r2, ln+off),
          q3 = __shfl(r3, ln+off), q4 = __shfl(r4, ln+off);
    if (ln > 63 - off) { q1 = 0.f; q2 = 0.f; q3 = 0.f; q4 = 0.f; }
    r1 += Pa.x*q1 + Pa.y*q2 + Pa.z*q3 + Pa.w*q4;
    r2 += Pb.x*q1 + Pb.y*q2 + Pb.z*q3 + Pb.w*q4;
    r3 += Pc.x*q1 + Pc.y*q2 + Pc.z*q3 + Pc.w*q4;
    r4 += Pd.x*q1 + Pd.y*q2 + Pd.z*q3 + Pd.w*q4;
  }
  if (ln == 0) LS[WB_OFF + (15 - w)] = make_float4(r1, r2, r3, r4);
  __syncthreads();                                        // BARRIER 2

  W1 = 0.f; W2 = 0.f; W3 = 0.f; W4 = 0.f;
  {
    float4 Bg = LS[WB_OFF + (ln & 15)];
    float t1 = Bg.x, t2 = Bg.y, t3 = Bg.z, t4 = Bg.w;
#pragma unroll
    for (int k = 0; k < 4; k++) {
      const float4 Pa = LS[4*(6+k)+0], Pb = LS[4*(6+k)+1],
                   Pc = LS[4*(6+k)+2], Pd = LS[4*(6+k)+3];
      const int off = 1 << k;
      float q1 = __shfl(t1, ln-off), q2 = __shfl(t2, ln-off),
            q3 = __shfl(t3, ln-off), q4 = __shfl(t4, ln-off);
      if (ln < off) { q1 = 0.f; q2 = 0.f; q3 = 0.f; q4 = 0.f; }
      t1 += Pa.x*q1 + Pa.y*q2 + Pa.z*q3 + Pa.w*q4;
      t2 += Pb.x*q1 + Pb.y*q2 + Pb.z*q3 + Pb.w*q4;
      t3 += Pc.x*q1 + Pc.y*q2 + Pc.z*q3 + Pc.w*q4;
      t4 += Pd.x*q1 + Pd.y*q2 + Pd.z*q3 + Pd.w*q4;
    }
    const int u = 15 - w;
    if (u > 0) { W1 = __shfl(t1, u-1); W2 = __shfl(t2, u-1);
                 W3 = __shfl(t3, u-1); W4 = __shfl(t4, u-1); }
  }
  {
    const float4 Pa = LS[0], Pb = LS[1], Pc = LS[2], Pd = LS[3];
    float i1 = Pa.x*W1 + Pa.y*W2 + Pa.z*W3 + Pa.w*W4;
    float i2 = Pb.x*W1 + Pb.y*W2 + Pb.z*W3 + Pb.w*W4;
    float i3 = Pc.x*W1 + Pc.y*W2 + Pc.z*W3 + Pc.w*W4;
    float i4 = Pd.x*W1 + Pd.y*W2 + Pd.z*W3 + Pd.w*W4;
    r1 = o1 + (ln==63 ? i1 : 0.f); r2 = o2 + (ln==63 ? i2 : 0.f);
    r3 = o3 + (ln==63 ? i3 : 0.f); r4 = o4 + (ln==63 ? i4 : 0.f);
  }
#pragma unroll
  for (int k = 0; k < 6; k++) {
    const float4 Pa = LS[4*k+0], Pb = LS[4*k+1], Pc = LS[4*k+2], Pd = LS[4*k+3];
    const int off = 1 << k;
    float q1 = __shfl(r1, ln+off), q2 = __shfl(r2, ln+off),
          q3 = __shfl(r3, ln+off), q4 = __shfl(r4, ln+off);
    if (ln > 63 - off) { q1 = 0.f; q2 = 0.f; q3 = 0.f; q4 = 0.f; }
    r1 += Pa.x*q1 + Pa.y*q2 + Pa.z*q3 + Pa.w*q4;
    r2 += Pb.x*q1 + Pb.y*q2 + Pb.z*q3 + Pb.w*q4;
    r3 += Pc.x*q1 + Pc.y*q2 + Pc.z*q3 + Pc.w*q4;
    r4 += Pd.x*q1 + Pd.y*q2 + Pd.z*q3 + Pd.w*q4;
  }
  s1 = __shfl(r1, ln+1); s2 = __shfl(r2, ln+1);
  s3 = __shfl(r3, ln+1); s4 = __shfl(r4, ln+1);
  if (ln == 63) { s1 = W1; s2 = W2; s3 = W3; s4 = W4; }

  // ---- backward phase 2 into z slots
  {
    float g1 = s1, g2 = s2, g3 = s3, g4 = s4;
#pragma unroll
    for (int m = 0; m < 48; m++) {
      float h = fmaf(na1, g1, fmaf(na2, g2, fmaf(na3, g3, na4 * g4)));
      if      (m == 0) h3v += h;
      else if (m == 1) h2v += h;
      else if (m == 2) h1v += h;
      else if (m == 3) h0  += h;
      else             A[51 - m] += h;
      g4 = g3; g3 = g2; g2 = g1; g1 = h;
    }
  }

  // ---- store staging: wave-private slice, 8 rounds, 0 barriers
  const int sbf = 4 * sb4;
  for (int r8 = 0; r8 < 8; r8++) {
    asm volatile("s_waitcnt lgkmcnt(0)" ::: "memory");
    __builtin_amdgcn_wave_barrier();
    const int c0 = 64*w + 8*r8;
    if ((ln >> 3) == r8) {
      const int D = ln & 7;
      const int zb = sbf + 52*D;
#pragma unroll
      for (int k4 = 0; k4 < 11; k4++)
        *reinterpret_cast<float4*>(&LSf[zb + 4*k4]) =
            make_float4(A[4*k4+4], A[4*k4+5], A[4*k4+6], A[4*k4+7]);
      *reinterpret_cast<float4*>(&LSf[zb + 44]) = make_float4(h0, h1v, h2v, h3v);
      if (D == 0) {                       // seam head scalars (z[47],z[46],z[45])
        int th = 48*c0 - 15;
        if ((unsigned)(th)   < 48000u) os[th]   = A[4];
        if ((unsigned)(th+1) < 48000u) os[th+1] = A[5];
        if ((unsigned)(th+2) < 48000u) os[th+2] = A[6];
      }
      if (D == 7) {                       // seam tail scalar (z[0])
        int tt = 48*c0 + 368;
        if ((unsigned)tt < 48000u) os[tt] = h3v;
      }
    }
    asm volatile("s_waitcnt lgkmcnt(0)" ::: "memory");
    __builtin_amdgcn_wave_barrier();
#pragma unroll
    for (int t2 = 0; t2 < 2; t2++) {
      int g = 64*t2 + ln;
      if (g < 95) {
        int j4 = 12*c0 - 3 + g;
        if ((unsigned)j4 < 12000u) {
          int idx0 = 3 + 4*g;
          int Dg = idx0 / 48;
          int rem = idx0 - 48*Dg;
          int base = sbf + 52*Dg + rem;
          float v0 = LSf[base];
          float v1 = LSf[base + 1 + (rem+1 >= 48 ? 4 : 0)];
          float v2 = LSf[base + 2 + (rem+2 >= 48 ? 4 : 0)];
          float v3 = LSf[base + 3 + (rem+3 >= 48 ? 4 : 0)];
          os4[j4] = make_float4(v0, v1, v2, v3);
        }
      }
    }
  }
}

extern "C" void kernel_launch(void* const* d_in, const int* in_sizes, int n_in,
                              void* d_out, int out_size, void* d_ws, size_t ws_size,
                              hipStream_t stream) {
  (void)n_in; (void)d_ws; (void)ws_size; (void)out_size;
  const float* x = (const float*)d_in[0];
  const float* b = (const float*)d_in[1];
  const float* a = (const float*)d_in[2];
  float* out = (float*)d_out;
  const int nseq = in_sizes[0] / T48;   // 512
  filtfilt_k<<<dim3(nseq), dim3(1024), 0, stream>>>(x, b, a, out);
}